// Round 1
// baseline (614.978 us; speedup 1.0000x reference)
//
#include <hip/hip_runtime.h>
#include <hip/hip_bf16.h>
#include <cstdint>
#include <cstddef>

// Problem constants
#define D_DIM 16384   // random feature dim
#define S_DIM 4096    // n_states
#define A_DIM 512     // n_actions
#define K_DIM 128     // state_dim
#define B_DIM 16      // batch

typedef float f32x4 __attribute__((ext_vector_type(4)));
typedef short s16x8 __attribute__((ext_vector_type(8)));
typedef unsigned short u16;
typedef unsigned int   u32;

__device__ __forceinline__ u16 bf16bits(float x) {
    return __builtin_bit_cast(u16, (__bf16)x);
}
__device__ __forceinline__ s16x8 frag_cast(uint4 u) {
    return __builtin_bit_cast(s16x8, u);
}

// ---------------------------------------------------------------------------
// Prep: W -> bf16 row-major [D][128]; Q[k][s] -> QT bf16 [S][128];
// obs[b][s] -> packed bf16 B-fragment layout obsP[(s>>3)][b][s&7]
// ---------------------------------------------------------------------------
__global__ void prep_kernel(const float* __restrict__ W, const float* __restrict__ Q,
                            const float* __restrict__ obs,
                            u16* __restrict__ Wb, u16* __restrict__ QT, u16* __restrict__ obsP)
{
    const int i0 = blockIdx.x * 256 + threadIdx.x;
    const int stride = gridDim.x * 256;
    for (int i = i0; i < D_DIM * K_DIM; i += stride)
        Wb[i] = bf16bits(W[i]);
    for (int i = i0; i < K_DIM * S_DIM; i += stride) {     // i = k*4096 + s (coalesced read)
        int k = i >> 12, s = i & 4095;
        QT[s * 128 + k] = bf16bits(Q[i]);
    }
    for (int i = i0; i < B_DIM * S_DIM; i += stride) {     // i = b*4096 + s
        int b = i >> 12, s = i & 4095;
        obsP[((s >> 3) << 7) + (b << 3) + (s & 7)] = bf16bits(obs[i]);
    }
}

// v[k][b] = sum_a V[k][a] * action[b][a]     (tiny: 128x16 outputs, K=512)
__global__ void kv_kernel(const float* __restrict__ V, const float* __restrict__ act,
                          float* __restrict__ v)
{
    const int i = blockIdx.x * 256 + threadIdx.x;   // 2048 threads
    const int k = i >> 4, b = i & 15;
    float s = 0.f;
    for (int a = 0; a < A_DIM; ++a) s += V[k * A_DIM + a] * act[b * A_DIM + a];
    v[i] = s;   // v[k*16+b]
}

// phi_v[d][b] = exp(i * (W@v)[d][b]) / 128   (accurate libm trig; |z2| can be ~40)
__global__ void phiv_kernel(const float* __restrict__ W, const float* __restrict__ v,
                            float* __restrict__ pvr, float* __restrict__ pvi)
{
    const int i = blockIdx.x * 256 + threadIdx.x;   // D*16 threads
    const int d = i >> 4, b = i & 15;
    float z = 0.f;
    for (int k = 0; k < K_DIM; ++k) z += W[d * K_DIM + k] * v[k * 16 + b];
    pvr[i] = cosf(z) * 0.0078125f;   // includes 1/sqrt(D)
    pvi[i] = sinf(z) * 0.0078125f;
}

// ---------------------------------------------------------------------------
// Fused phi-GEMM pass.
//  Inner:  z[16 x 64] = P1[mstrip,0:128] @ P2[0:128, kchunk]  (bf16 MFMA, K=128)
//  Trig:   cos/sin(z) -> packed u32(bf16cos|bf16sin) -> wave-private swizzled LDS
//  Outer:  MODE 0: out1 += cos @ y1 ; out2 += sin @ y1      (passes A, C)
//          MODE 1: out1 += cos @ y1 + sin @ y2              (passes B, D)
//  Each wave owns one 16-row M-strip; grid.y = K-split; f32 atomicAdd epilogue.
//  P1: [M][128] bf16 row-major. P2: [Kdim][128] bf16 row-major (used transposed).
//  y*: packed B-frag layout [(k>>3)][n][k&7] bf16.
// ---------------------------------------------------------------------------
template<int MODE>
__global__ __launch_bounds__(256, 4)
void fused_pass(const u16* __restrict__ P1, const u16* __restrict__ P2,
                const u16* __restrict__ y1, const u16* __restrict__ y2,
                float* __restrict__ out1, float* __restrict__ out2)
{
    __shared__ u32 lds[4][16][64];   // per-wave 16 rows x 64 packed cols, XOR-swizzled
    const int tid = threadIdx.x;
    const int w   = tid >> 6;
    const int l   = tid & 63;
    const int n0  = l & 15;
    const int hi  = l >> 4;
    const int mstrip = blockIdx.x * 64 + w * 16;
    const int kbase0 = blockIdx.y * 1024;   // 16 chunks of 64 per split

    // Inner A-fragments: P1 rows [mstrip..mstrip+15], K=128 -> 4 MFMA K-steps
    s16x8 afrag[4];
    {
        const uint4* ap = (const uint4*)(P1 + (size_t)(mstrip + n0) * 128);
        #pragma unroll
        for (int ki = 0; ki < 4; ++ki) afrag[ki] = frag_cast(ap[4 * ki + hi]);
    }

    f32x4 acc1 = {0.f, 0.f, 0.f, 0.f};
    f32x4 acc2 = {0.f, 0.f, 0.f, 0.f};

    for (int c = 0; c < 16; ++c) {
        const int kbase = kbase0 + c * 64;

        // ---- inner MFMA: z tile [16 x 64] ----
        f32x4 zc[4];
        #pragma unroll
        for (int t = 0; t < 4; ++t) zc[t] = f32x4{0.f, 0.f, 0.f, 0.f};
        #pragma unroll
        for (int t = 0; t < 4; ++t) {
            const uint4* bp = (const uint4*)(P2 + (size_t)(kbase + 16 * t + n0) * 128);
            #pragma unroll
            for (int ki = 0; ki < 4; ++ki)
                zc[t] = __builtin_amdgcn_mfma_f32_16x16x32_bf16(afrag[ki], frag_cast(bp[4 * ki + hi]), zc[t], 0, 0, 0);
        }

        // ---- trig + pack + LDS write (C-frag: row=4*hi+r, col=16*t+n0) ----
        #pragma unroll
        for (int t = 0; t < 4; ++t) {
            #pragma unroll
            for (int r = 0; r < 4; ++r) {
                float rv = zc[t][r] * 0.15915494309189535f;   // radians -> revolutions
                rv -= floorf(rv);
                const float cz = __builtin_amdgcn_cosf(rv);
                const float sz = __builtin_amdgcn_sinf(rv);
                const u32 pk = (u32)bf16bits(cz) | ((u32)bf16bits(sz) << 16);
                const int row  = 4 * hi + r;
                const int col  = 16 * t + n0;
                const int wcol = (col & 3) | ((((col >> 2) ^ row) & 15) << 2);  // 16B-chunk XOR swizzle
                lds[w][row][wcol] = pk;
            }
        }
        // wave-private LDS: no barrier needed; compiler orders ds ops with lgkmcnt.

        // ---- outer MFMA: A-frag row = n0, k = 32*ks + 8*hi + j ----
        #pragma unroll
        for (int ks = 0; ks < 2; ++ks) {
            const int cc0 = 8 * ks + 2 * hi;
            const uint4 r0 = *(const uint4*)&lds[w][n0][((cc0    ) ^ n0) << 2];
            const uint4 r1 = *(const uint4*)&lds[w][n0][((cc0 + 1) ^ n0) << 2];
            uint4 cu, su;
            cu.x = (r0.x & 0xffffu) | (r0.y << 16);
            cu.y = (r0.z & 0xffffu) | (r0.w << 16);
            cu.z = (r1.x & 0xffffu) | (r1.y << 16);
            cu.w = (r1.z & 0xffffu) | (r1.w << 16);
            su.x = (r0.x >> 16) | (r0.y & 0xffff0000u);
            su.y = (r0.z >> 16) | (r0.w & 0xffff0000u);
            su.z = (r1.x >> 16) | (r1.y & 0xffff0000u);
            su.w = (r1.z >> 16) | (r1.w & 0xffff0000u);
            const s16x8 cfrag = frag_cast(cu);
            const s16x8 sfrag = frag_cast(su);
            const size_t yg = (size_t)((kbase >> 3) + 4 * ks + hi) * 128 + (size_t)n0 * 8;
            const s16x8 yf1 = frag_cast(*(const uint4*)(y1 + yg));
            if (MODE == 0) {
                acc1 = __builtin_amdgcn_mfma_f32_16x16x32_bf16(cfrag, yf1, acc1, 0, 0, 0);
                acc2 = __builtin_amdgcn_mfma_f32_16x16x32_bf16(sfrag, yf1, acc2, 0, 0, 0);
            } else {
                const s16x8 yf2 = frag_cast(*(const uint4*)(y2 + yg));
                acc1 = __builtin_amdgcn_mfma_f32_16x16x32_bf16(cfrag, yf1, acc1, 0, 0, 0);
                acc1 = __builtin_amdgcn_mfma_f32_16x16x32_bf16(sfrag, yf2, acc1, 0, 0, 0);
            }
        }
    }

    // ---- epilogue: f32 atomic reduction across K-splits ----
    #pragma unroll
    for (int r = 0; r < 4; ++r) {
        const int orow = mstrip + 4 * hi + r;
        atomicAdd(&out1[orow * 16 + n0], acc1[r]);
        if (MODE == 0) atomicAdd(&out2[orow * 16 + n0], acc2[r]);
    }
}

// state = acc/128 -> bf16 packed B-frag layout (re, im)
__global__ void finishA(const float* __restrict__ ar, const float* __restrict__ ai,
                        u16* __restrict__ pr, u16* __restrict__ pi)
{
    const int i = blockIdx.x * 256 + threadIdx.x;   // D*16
    const int d = i >> 4, b = i & 15;
    const int p = ((d >> 3) << 7) + (b << 3) + (d & 7);
    pr[p] = bf16bits(ar[i] * 0.0078125f);
    pi[p] = bf16bits(ai[i] * 0.0078125f);
}

// out_state = (acc/128) * phi_v   (complex mult) -> bf16 packed
__global__ void finishC(const float* __restrict__ ar, const float* __restrict__ ai,
                        const float* __restrict__ pvr, const float* __restrict__ pvi,
                        u16* __restrict__ pr, u16* __restrict__ pi)
{
    const int i = blockIdx.x * 256 + threadIdx.x;   // D*16
    const int d = i >> 4, b = i & 15;
    const float nr = ar[i] * 0.0078125f, ni = ai[i] * 0.0078125f;
    const float xr = nr * pvr[i] - ni * pvi[i];
    const float xi = nr * pvi[i] + ni * pvr[i];
    const int p = ((d >> 3) << 7) + (b << 3) + (d & 7);
    pr[p] = bf16bits(xr);
    pi[p] = bf16bits(xi);
}

// Column softmax over s (4096) per b. OUT=0: write bf16 packed weights.
// OUT=1: write f32 result [s][b] (final output layout).
template<int OUT>
__global__ void softmax_col(const float* __restrict__ acc, u16* __restrict__ wp,
                            float* __restrict__ outp)
{
    const int b = blockIdx.x;
    const int tid = threadIdx.x;   // 256
    __shared__ float red[4];
    float x[16];
    float m = -1e30f;
    #pragma unroll
    for (int j = 0; j < 16; ++j) {
        x[j] = acc[(j * 256 + tid) * 16 + b] * 0.0078125f;   // apply 1/sqrt(D)
        m = fmaxf(m, x[j]);
    }
    #pragma unroll
    for (int off = 1; off < 64; off <<= 1) m = fmaxf(m, __shfl_xor(m, off, 64));
    if ((tid & 63) == 0) red[tid >> 6] = m;
    __syncthreads();
    m = fmaxf(fmaxf(red[0], red[1]), fmaxf(red[2], red[3]));
    float sum = 0.f;
    #pragma unroll
    for (int j = 0; j < 16; ++j) { x[j] = expf(x[j] - m); sum += x[j]; }
    #pragma unroll
    for (int off = 1; off < 64; off <<= 1) sum += __shfl_xor(sum, off, 64);
    __syncthreads();
    if ((tid & 63) == 0) red[tid >> 6] = sum;
    __syncthreads();
    const float inv = 1.0f / (red[0] + red[1] + red[2] + red[3]);
    #pragma unroll
    for (int j = 0; j < 16; ++j) {
        const int s = j * 256 + tid;
        const float val = x[j] * inv;
        if (OUT == 0) wp[((s >> 3) << 7) + (b << 3) + (s & 7)] = bf16bits(val);
        else          outp[s * 16 + b] = val;
    }
}

// ---------------------------------------------------------------------------
extern "C" void kernel_launch(void* const* d_in, const int* in_sizes, int n_in,
                              void* d_out, int out_size, void* d_ws, size_t ws_size,
                              hipStream_t stream)
{
    const float* obs = (const float*)d_in[0];
    const float* act = (const float*)d_in[1];
    const float* Q   = (const float*)d_in[2];
    const float* V   = (const float*)d_in[3];
    const float* W   = (const float*)d_in[4];
    float* out = (float*)d_out;
    char* ws = (char*)d_ws;

    // workspace layout (bytes)
    u16*   Wb     = (u16*)  (ws + 0);          // 4 MB   bf16 W [D][128]
    u16*   QT     = (u16*)  (ws + 4194304);    // 1 MB   bf16 Q^T [S][128]
    u16*   obsP   = (u16*)  (ws + 5242880);    // 128 KB packed obs
    u16*   wP     = (u16*)  (ws + 5373952);    // 128 KB packed weights
    u16*   stRe   = (u16*)  (ws + 5505024);    // 512 KB packed state re
    u16*   stIm   = (u16*)  (ws + 6029312);    // 512 KB packed state im
    u16*   osRe   = (u16*)  (ws + 6553600);    // 512 KB packed out_state re
    u16*   osIm   = (u16*)  (ws + 7077888);    // 512 KB packed out_state im
    float* pvR    = (float*)(ws + 7602176);    // 1 MB   phi_v re (incl 1/128)
    float* pvI    = (float*)(ws + 8650752);    // 1 MB   phi_v im
    float* vv     = (float*)(ws + 9699328);    // 8 KB   v[k][b]
    float* accAre = (float*)(ws + 9707520);    // 1 MB   pass A acc re
    float* accAim = (float*)(ws + 10756096);   // 1 MB   pass A acc im
    float* accCre = (float*)(ws + 11804672);   // 1 MB   pass C acc re
    float* accCim = (float*)(ws + 12853248);   // 1 MB   pass C acc im
    float* scB    = (float*)(ws + 13901824);   // 256 KB pass B scores acc
    float* scD    = (float*)(ws + 14163968);   // 256 KB pass D scores acc

    // zero the atomic accumulators (contiguous region)
    hipMemsetAsync(ws + 9707520, 0, 4718592, stream);

    prep_kernel<<<1024, 256, 0, stream>>>(W, Q, obs, Wb, QT, obsP);
    kv_kernel<<<8, 256, 0, stream>>>(V, act, vv);
    phiv_kernel<<<1024, 256, 0, stream>>>(W, vv, pvR, pvI);

    // pass A: state = phi @ obs^T      (M=D grid 256x4 split)
    fused_pass<0><<<dim3(256, 4), 256, 0, stream>>>(Wb, QT, obsP, obsP, accAre, accAim);
    finishA<<<1024, 256, 0, stream>>>(accAre, accAim, stRe, stIm);

    // pass B: scores = Re(phi^H @ state)   (M=S grid 64x16 split)
    fused_pass<1><<<dim3(64, 16), 256, 0, stream>>>(QT, Wb, stRe, stIm, scB, scB);
    softmax_col<0><<<16, 256, 0, stream>>>(scB, wP, nullptr);

    // pass C: new_state = phi @ weights ; out_state = new_state * phi_v
    fused_pass<0><<<dim3(256, 4), 256, 0, stream>>>(Wb, QT, wP, wP, accCre, accCim);
    finishC<<<1024, 256, 0, stream>>>(accCre, accCim, pvR, pvI, osRe, osIm);

    // pass D: out = softmax(Re(phi^H @ out_state))
    fused_pass<1><<<dim3(64, 16), 256, 0, stream>>>(QT, Wb, osRe, osIm, scD, scD);
    softmax_col<1><<<16, 256, 0, stream>>>(scD, nullptr, out);
}